// Round 6
// baseline (523.338 us; speedup 1.0000x reference)
//
#include <hip/hip_runtime.h>
#include <hip/hip_bf16.h>

typedef __bf16 bf16x8 __attribute__((ext_vector_type(8)));
typedef float  f32x4  __attribute__((ext_vector_type(4)));

typedef __attribute__((address_space(1))) const void* as1p;
typedef __attribute__((address_space(3))) void*       as3p;

__device__ __forceinline__ void gl16(const void* g, void* l) {
    __builtin_amdgcn_global_load_lds((as1p)g, (as3p)l, 16, 0, 0);
}
#define MEMFENCE asm volatile("" ::: "memory")
#define BARRIER  do { MEMFENCE; __builtin_amdgcn_s_barrier(); MEMFENCE; } while (0)
#define LGKM0    asm volatile("s_waitcnt lgkmcnt(0)" ::: "memory")

// ---------------------------------------------------------------------------
// fp32 -> bf16 convert, 8 elements/thread, grid-stride
// ---------------------------------------------------------------------------
__global__ __launch_bounds__(256)
void cvt_f32_bf16(const float* __restrict__ in, __bf16* __restrict__ out, long n8)
{
    long i = (long)blockIdx.x * blockDim.x + threadIdx.x;
    const long stride = (long)gridDim.x * blockDim.x;
    for (; i < n8; i += stride) {
        f32x4 a = ((const f32x4*)in)[2*i];
        f32x4 b = ((const f32x4*)in)[2*i + 1];
        bf16x8 o;
        #pragma unroll
        for (int j = 0; j < 4; ++j) { o[j] = (__bf16)a[j]; o[4+j] = (__bf16)b[j]; }
        ((bf16x8*)out)[i] = o;
    }
}

__global__ __launch_bounds__(256)
void pack_bias(const float* __restrict__ a, const float* __restrict__ b,
               const float* __restrict__ c, float* __restrict__ o)
{
    int i = blockIdx.x * 256 + threadIdx.x;   // 3072 total
    const float* s = (i < 1024) ? a : (i < 2048) ? b : c;
    o[i] = s[i & 1023];
}

// ---------------------------------------------------------------------------
// 256x256-tile NT GEMM, BK=64, 8 waves (2Mx4N), m201-style 8-phase schedule.
// LDS 128 KB: A[d][h] = d*32768 + h*16384, B[d][h] = 65536 + d*32768 + h*16384
//   (d = K-tile parity double-buffer, h = M/N half, half = [128][64] bf16).
// Swizzle (involution on bits 4-6 within a half, row = byte>>7):
//   phys = logical ^ ((row & 7) << 4)   -> conflict-free wave64 ds_read_b128.
// 4 phases per K-tile, one C-quadrant (16 MFMA) per phase:
//   ph0: read a[0-3],b[0-1] | stage A1(t+1) | bar | lgkm0 | prio1 Q1 prio0 | bar
//   ph1: read b[2-3]        |                 bar | lgkm0 | prio1 Q2 prio0 | bar
//   ph2: read a[4-7]        | stage B0(t+2) | bar | lgkm0 | prio1 Q3 prio0 | bar
//   ph3:                    | stage B1,A0(t+2) |            prio1 Q4 prio0
//        vmcnt(6) [counted ledger: leaves exactly the 6 loads t+1 doesn't need]
//        bar
// EPI 0: +bias[col], bf16 out (z = weight)   EPI 1: exp(acc*alpha) + row psums
// EPI 2: f32 out / rowsum                    EPI 3: split-K f32 partials
// ---------------------------------------------------------------------------
template<int EPI>
__global__ __launch_bounds__(512, 2)
void gemm8p(const __bf16* __restrict__ A, const __bf16* __restrict__ B,
            void* __restrict__ C0, void* __restrict__ C1,
            const float* __restrict__ aux, float* __restrict__ psum,
            int ldA, int ldB, int ldC, int Ktiles,
            long szA, long szB, long szC, long szAux, long szPsum,
            int nkz, float alpha)
{
    __shared__ char lds[131072];

    const int tid  = threadIdx.x;
    const int wave = tid >> 6, lane = tid & 63;
    const int wm = wave >> 2, wn = wave & 3;          // 2 x 4 wave grid
    const int rl = lane & 15, kg = lane >> 4;
    const int z  = blockIdx.z;

    const __bf16* Ab = A + (long)z * ((EPI == 0) ? 0 : szA);
    const __bf16* Bb = B + (long)z * szB;

    // ---- staging: thread covers phys granules P=tid*16 and P+8192 per half.
    // logical col = (P & 127) ^ ((row & 7) << 4); row = P>>7 (XOR keeps row).
    const int P     = tid * 16;
    const int srow  = P >> 7;                         // 0..63
    const int scolb = (P & 127) ^ ((srow & 7) << 4);  // byte col in 128B row
    const long rbA = (long)ldA * 2;
    const long rbB = (long)ldB * 2;
    const char* gA = (const char*)Ab + ((long)blockIdx.x * 256 + srow) * rbA + scolb;
    const char* gB = (const char*)Bb + ((long)blockIdx.y * 256 + srow) * rbB + scolb;

    auto stageA = [&](int d, int h, int kt) {
        const char* s = gA + (long)h * 128 * rbA + (long)kt * 128;
        char* dst = lds + d * 32768 + h * 16384 + wave * 1024;
        gl16(s, dst);
        gl16(s + 64 * rbA, dst + 8192);
    };
    auto stageB = [&](int d, int h, int kt) {
        const char* s = gB + (long)h * 128 * rbB + (long)kt * 128;
        char* dst = lds + 65536 + d * 32768 + h * 16384 + wave * 1024;
        gl16(s, dst);
        gl16(s + 64 * rbB, dst + 8192);
    };

    // ---- fragment reads: within a half, logical byte = row*128 + ks*64 + kg*16,
    // row = (mi|ni)*16 + rl  ->  phys col XOR (rl&7)<<4.
    const int csw[2] = { (kg << 4) ^ ((rl & 7) << 4),
                         ((kg << 4) ^ ((rl & 7) << 4)) ^ 64 };
    const int aoff = rl * 128;                    // + mi*2048 + csw[ks]
    const int boff = ((wn & 1) * 64 + rl) * 128;  // + ni*2048 + csw[ks]

    // ---- prologue: tiles 0 and 1 fully staged; wait tile0 (tile1's 8 may fly)
    stageA(0, 0, 0); stageA(0, 1, 0); stageB(0, 0, 0); stageB(0, 1, 0);
    if (Ktiles > 1) {
        stageA(1, 0, 1); stageA(1, 1, 1); stageB(1, 0, 1); stageB(1, 1, 1);
        asm volatile("s_waitcnt vmcnt(8)" ::: "memory");
    } else {
        asm volatile("s_waitcnt vmcnt(0)" ::: "memory");
    }
    BARRIER;

    f32x4 acc[8][4] = {};

    for (int t = 0; t < Ktiles; ++t) {
        const int d = t & 1, nd = d ^ 1;
        const char* rA = lds + d * 32768 + wm * 16384;
        const char* rB = lds + 65536 + d * 32768 + (wn >> 1) * 16384;
        bf16x8 a[4][2], b[4][2];

        // ---------------- ph0: read a[0-3], b[0-1]; stage A1(t+1)
        #pragma unroll
        for (int mi = 0; mi < 4; ++mi)
            #pragma unroll
            for (int ks = 0; ks < 2; ++ks)
                a[mi][ks] = *(const bf16x8*)(rA + aoff + mi * 2048 + csw[ks]);
        #pragma unroll
        for (int ni = 0; ni < 2; ++ni)
            #pragma unroll
            for (int ks = 0; ks < 2; ++ks)
                b[ni][ks] = *(const bf16x8*)(rB + boff + ni * 2048 + csw[ks]);
        if (t >= 1 && t + 1 < Ktiles) stageA(nd, 1, t + 1);
        BARRIER;
        LGKM0;
        __builtin_amdgcn_s_setprio(1);
        #pragma unroll
        for (int mi = 0; mi < 4; ++mi)
            #pragma unroll
            for (int ni = 0; ni < 2; ++ni)
                #pragma unroll
                for (int ks = 0; ks < 2; ++ks)
                    acc[mi][ni] = __builtin_amdgcn_mfma_f32_16x16x32_bf16(
                        a[mi][ks], b[ni][ks], acc[mi][ni], 0, 0, 0);
        __builtin_amdgcn_s_setprio(0);
        BARRIER;

        // ---------------- ph1: read b[2-3]
        #pragma unroll
        for (int ni = 2; ni < 4; ++ni)
            #pragma unroll
            for (int ks = 0; ks < 2; ++ks)
                b[ni][ks] = *(const bf16x8*)(rB + boff + ni * 2048 + csw[ks]);
        BARRIER;
        LGKM0;
        __builtin_amdgcn_s_setprio(1);
        #pragma unroll
        for (int mi = 0; mi < 4; ++mi)
            #pragma unroll
            for (int ni = 2; ni < 4; ++ni)
                #pragma unroll
                for (int ks = 0; ks < 2; ++ks)
                    acc[mi][ni] = __builtin_amdgcn_mfma_f32_16x16x32_bf16(
                        a[mi][ks], b[ni][ks], acc[mi][ni], 0, 0, 0);
        __builtin_amdgcn_s_setprio(0);
        BARRIER;

        // ---------------- ph2: read a[4-7]; stage B0(t+2)
        #pragma unroll
        for (int mi = 0; mi < 4; ++mi)
            #pragma unroll
            for (int ks = 0; ks < 2; ++ks)
                a[mi][ks] = *(const bf16x8*)(rA + aoff + (4 + mi) * 2048 + csw[ks]);
        if (t + 2 < Ktiles) stageB(d, 0, t + 2);
        BARRIER;
        LGKM0;
        __builtin_amdgcn_s_setprio(1);
        #pragma unroll
        for (int mi = 0; mi < 4; ++mi)
            #pragma unroll
            for (int ni = 0; ni < 2; ++ni)
                #pragma unroll
                for (int ks = 0; ks < 2; ++ks)
                    acc[4 + mi][ni] = __builtin_amdgcn_mfma_f32_16x16x32_bf16(
                        a[mi][ks], b[ni][ks], acc[4 + mi][ni], 0, 0, 0);
        __builtin_amdgcn_s_setprio(0);
        BARRIER;

        // ---------------- ph3: stage B1(t+2), A0(t+2); Q4; counted vmcnt
        if (t + 2 < Ktiles) { stageB(d, 1, t + 2); stageA(d, 0, t + 2); }
        __builtin_amdgcn_s_setprio(1);
        #pragma unroll
        for (int mi = 0; mi < 4; ++mi)
            #pragma unroll
            for (int ni = 2; ni < 4; ++ni)
                #pragma unroll
                for (int ks = 0; ks < 2; ++ks)
                    acc[4 + mi][ni] = __builtin_amdgcn_mfma_f32_16x16x32_bf16(
                        a[mi][ks], b[ni][ks], acc[4 + mi][ni], 0, 0, 0);
        __builtin_amdgcn_s_setprio(0);
        if (t + 2 < Ktiles)      asm volatile("s_waitcnt vmcnt(6)" ::: "memory");
        else if (t + 1 < Ktiles) asm volatile("s_waitcnt vmcnt(0)" ::: "memory");
        if (t + 1 < Ktiles) BARRIER;
    }

    // ---- epilogue (C/D layout: row = (lane>>4)*4+j, col = lane&15)
    const int rowg = blockIdx.x * 256 + wm * 128 + kg * 4;
    const int colg = blockIdx.y * 256 + wn * 64 + rl;

    if (EPI == 0) {
        __bf16* C = (__bf16*)C0 + (long)z * szC;
        const float* bbv = aux + (long)z * szAux;
        float bv[4];
        #pragma unroll
        for (int ni = 0; ni < 4; ++ni) bv[ni] = bbv[colg + ni * 16];
        #pragma unroll
        for (int mi = 0; mi < 8; ++mi)
            #pragma unroll
            for (int j = 0; j < 4; ++j) {
                __bf16* cr = C + (long)(rowg + mi * 16 + j) * ldC + colg;
                #pragma unroll
                for (int ni = 0; ni < 4; ++ni)
                    cr[ni * 16] = (__bf16)(acc[mi][ni][j] + bv[ni]);
            }
    } else if (EPI == 1) {
        BARRIER;                               // LDS about to be reused (wsum)
        __bf16* C = (__bf16*)C0 + (long)z * szC;
        float* wsum = (float*)lds;
        float rsm[8][4];
        #pragma unroll
        for (int mi = 0; mi < 8; ++mi)
            #pragma unroll
            for (int j = 0; j < 4; ++j) {
                float s = 0.f;
                __bf16* cr = C + (long)(rowg + mi * 16 + j) * ldC + colg;
                #pragma unroll
                for (int ni = 0; ni < 4; ++ni) {
                    float e = __expf(acc[mi][ni][j] * alpha);
                    cr[ni * 16] = (__bf16)e;
                    s += e;
                }
                rsm[mi][j] = s;
            }
        #pragma unroll
        for (int mi = 0; mi < 8; ++mi)
            #pragma unroll
            for (int j = 0; j < 4; ++j) {
                float s = rsm[mi][j];
                s += __shfl_xor(s, 1); s += __shfl_xor(s, 2);
                s += __shfl_xor(s, 4); s += __shfl_xor(s, 8);
                rsm[mi][j] = s;
            }
        if (rl == 0) {
            #pragma unroll
            for (int mi = 0; mi < 8; ++mi)
                #pragma unroll
                for (int j = 0; j < 4; ++j)
                    wsum[wn * 256 + wm * 128 + mi * 16 + kg * 4 + j] = rsm[mi][j];
        }
        __syncthreads();
        if (tid < 256) {
            float s = wsum[tid] + wsum[256 + tid] + wsum[512 + tid] + wsum[768 + tid];
            psum[(long)z * szPsum + (long)blockIdx.y * 4096 + blockIdx.x * 256 + tid] = s;
        }
    } else if (EPI == 2) {
        float* C = (float*)C0 + (long)z * szC;
        const float* rs = aux + (long)z * szAux;
        #pragma unroll
        for (int mi = 0; mi < 8; ++mi)
            #pragma unroll
            for (int j = 0; j < 4; ++j) {
                int r = rowg + mi * 16 + j;
                float inv = 1.f / rs[r];
                float* cr = C + (long)r * ldC + colg;
                #pragma unroll
                for (int ni = 0; ni < 4; ++ni) cr[ni * 16] = acc[mi][ni][j] * inv;
            }
    } else {
        float* C = (z < nkz - 1) ? ((float*)C0 + (long)z * szC) : (float*)C1;
        #pragma unroll
        for (int mi = 0; mi < 8; ++mi)
            #pragma unroll
            for (int j = 0; j < 4; ++j) {
                float* cr = C + (long)(rowg + mi * 16 + j) * ldC + colg;
                #pragma unroll
                for (int ni = 0; ni < 4; ++ni) cr[ni * 16] = acc[mi][ni][j];
            }
    }
}

// ---------------------------------------------------------------------------
// bf16 transpose: in [T][D] -> out [D][T], 64x64 tiles via LDS
// ---------------------------------------------------------------------------
__global__ __launch_bounds__(256)
void transpose64(const __bf16* __restrict__ in, __bf16* __restrict__ out,
                 int T, int D, long sIn, long sOut)
{
    __shared__ __bf16 tile[64][72];
    const __bf16* pin  = in  + (long)blockIdx.z * sIn;
    __bf16*       pout = out + (long)blockIdx.z * sOut;
    const int t0 = blockIdx.x * 64, d0 = blockIdx.y * 64;
    const int tid = threadIdx.x;
    const int rr = tid >> 3;
    const int cc = (tid & 7) * 8;

    #pragma unroll
    for (int it = 0; it < 2; ++it) {
        int r = rr + it * 32;
        bf16x8 v = *(const bf16x8*)(pin + (long)(t0 + r) * D + d0 + cc);
        *(bf16x8*)&tile[r][cc] = v;
    }
    __syncthreads();
    #pragma unroll
    for (int it = 0; it < 2; ++it) {
        int dr = rr + it * 32;
        bf16x8 o;
        #pragma unroll
        for (int j = 0; j < 8; ++j) o[j] = tile[cc + j][dr];
        *(bf16x8*)(pout + (long)(d0 + dr) * T + t0 + cc) = o;
    }
}

// rs[b][r] = sum_{cb<16} psum[b][cb][r]
__global__ __launch_bounds__(256)
void rowsum16(const float* __restrict__ psum, float* __restrict__ rs)
{
    int i = blockIdx.x * 256 + threadIdx.x;
    int b = i >> 12, r = i & 4095;
    const float* p = psum + (long)b * 65536 + r;
    float s = 0.f;
    #pragma unroll
    for (int cb = 0; cb < 16; ++cb) s += p[cb * 4096];
    rs[i] = s;
}

// out = (out + sum parts) / rs[row]
__global__ __launch_bounds__(256)
void pv_reduce(float* __restrict__ outb, const float* __restrict__ parts,
               int np, const float* __restrict__ rs)
{
    long i = ((long)blockIdx.x * 256 + threadIdx.x) * 4;
    f32x4 v = *(f32x4*)(outb + i);
    for (int p = 0; p < np; ++p)
        v += *(const f32x4*)(parts + (long)p * 4194304 + i);
    float inv = 1.f / rs[i >> 10];
    v *= inv;
    *(f32x4*)(outb + i) = v;
}

// ---------------------------------------------------------------------------
extern "C" void kernel_launch(void* const* d_in, const int* in_sizes, int n_in,
                              void* d_out, int out_size, void* d_ws, size_t ws_size,
                              hipStream_t stream)
{
    const float* x  = (const float*)d_in[0];
    const float* Wq = (const float*)d_in[1];
    const float* bq = (const float*)d_in[2];
    const float* Wk = (const float*)d_in[3];
    const float* bk = (const float*)d_in[4];
    const float* Wv = (const float*)d_in[5];
    const float* bv = (const float*)d_in[6];
    float* out = (float*)d_out;

    const long T = 4096, E = 1024, D = 1024;
    const long TD = T * D;
    const long TT = T * T;
    const long WB = D * E;
    const float ALPHA = 1.0f / 32.0f;
    char* W = (char*)d_ws;

    const size_t need_A  = 275853312;
    const size_t need_B2 = 191131648;

    if (ws_size >= need_A) {
        __bf16* wall = (__bf16*)(W);
        __bf16* xb   = (__bf16*)(W + 6291456);
        __bf16* vt   = (__bf16*)(W + 39845888);
        __bf16* q    = (__bf16*)(W + 73400320);
        __bf16* k    = (__bf16*)(W + 106954752);
        __bf16* P    = (__bf16*)(W + 140509184);
        float*  psum = (float*) (W + 274726912);
        float*  rs   = (float*) (W + 275775488);
        float*  bp   = (float*) (W + 275841024);

        pack_bias<<<12, 256, 0, stream>>>(bq, bk, bv, bp);
        cvt_f32_bf16<<<512, 256, 0, stream>>>(Wq, wall, WB/8);
        cvt_f32_bf16<<<512, 256, 0, stream>>>(Wk, wall + WB, WB/8);
        cvt_f32_bf16<<<512, 256, 0, stream>>>(Wv, wall + 2*WB, WB/8);
        cvt_f32_bf16<<<4096, 256, 0, stream>>>(x, xb, 4*TD/8);

        gemm8p<0><<<dim3(64,4,3), 512, 0, stream>>>(
            xb, wall, q, nullptr, bp, nullptr,
            1024, 1024, 1024, 16, 0, WB, 4*TD, 1024, 0, 0, 0.f);

        transpose64<<<dim3(64,16,4), 256, 0, stream>>>(P, vt, (int)T, (int)D, TD, TD);

        gemm8p<1><<<dim3(16,16,4), 512, 0, stream>>>(
            q, k, P, nullptr, nullptr, psum,
            1024, 1024, 4096, 16, TD, TD, TT, 0, 65536, 0, ALPHA);

        rowsum16<<<64, 256, 0, stream>>>(psum, rs);

        gemm8p<2><<<dim3(16,4,4), 512, 0, stream>>>(
            P, vt, out, nullptr, rs, nullptr,
            4096, 4096, 1024, 64, TT, TD, TD, 4096, 0, 0, 0.f);
    } else if (ws_size >= need_B2) {
        __bf16* wall  = (__bf16*)(W);
        __bf16* xb    = (__bf16*)(W + 6291456);
        float*  parts = (float*) (W + 6291456);
        __bf16* vt    = (__bf16*)(W + 56623104);
        __bf16* q     = (__bf16*)(W + 90177536);
        __bf16* k     = (__bf16*)(W + 123731968);
        __bf16* P     = (__bf16*)(W + 157286400);
        float*  psum  = (float*) (W + 190840832);
        float*  rs    = (float*) (W + 191102976);
        float*  bp    = (float*) (W + 191119360);

        pack_bias<<<12, 256, 0, stream>>>(bq, bk, bv, bp);
        cvt_f32_bf16<<<512, 256, 0, stream>>>(Wq, wall, WB/8);
        cvt_f32_bf16<<<512, 256, 0, stream>>>(Wk, wall + WB, WB/8);
        cvt_f32_bf16<<<512, 256, 0, stream>>>(Wv, wall + 2*WB, WB/8);
        cvt_f32_bf16<<<4096, 256, 0, stream>>>(x, xb, 4*TD/8);

        gemm8p<0><<<dim3(64,4,3), 512, 0, stream>>>(
            xb, wall, q, nullptr, bp, nullptr,
            1024, 1024, 1024, 16, 0, WB, 4*TD, 1024, 0, 0, 0.f);

        transpose64<<<dim3(64,16,4), 256, 0, stream>>>(P, vt, (int)T, (int)D, TD, TD);

        for (int b = 0; b < 4; ++b) {
            gemm8p<1><<<dim3(16,16,1), 512, 0, stream>>>(
                q + b*TD, k + b*TD, P, nullptr, nullptr, psum,
                1024, 1024, 4096, 16, 0, 0, 0, 0, 0, 0, ALPHA);
            rowsum16<<<16, 256, 0, stream>>>(psum, rs);
            gemm8p<3><<<dim3(16,4,4), 512, 0, stream>>>(
                P, vt + b*TD, parts, out + b*TD, nullptr, nullptr,
                4096, 4096, 1024, 16, 1024, 1024, TD, 0, 0, 4, 0.f);
            pv_reduce<<<4096, 256, 0, stream>>>(out + b*TD, parts, 3, rs);
        }
    } else {
        __bf16* wall  = (__bf16*)(W);
        __bf16* xb    = (__bf16*)(W + 6291456);
        float*  parts = (float*) (W + 6291456);
        __bf16* q     = (__bf16*)(W + 14680064);
        __bf16* k     = (__bf16*)(W + 23068672);
        __bf16* vt    = (__bf16*)(W + 31457280);
        __bf16* P     = (__bf16*)(W + 39845888);
        float*  psum  = (float*) (W + 73400320);
        float*  rs    = (float*) (W + 73662464);
        float*  bp    = (float*) (W + 73678848);

        pack_bias<<<12, 256, 0, stream>>>(bq, bk, bv, bp);
        cvt_f32_bf16<<<512, 256, 0, stream>>>(Wq, wall, WB/8);
        cvt_f32_bf16<<<512, 256, 0, stream>>>(Wk, wall + WB, WB/8);
        cvt_f32_bf16<<<512, 256, 0, stream>>>(Wv, wall + 2*WB, WB/8);

        for (int b = 0; b < 4; ++b) {
            cvt_f32_bf16<<<2048, 256, 0, stream>>>(x + b*TD, xb, TD/8);
            gemm8p<0><<<dim3(16,4,1), 512, 0, stream>>>(
                xb, wall, q, nullptr, bp, nullptr,
                1024, 1024, 1024, 16, 0, 0, 0, 0, 0, 0, 0.f);
            gemm8p<0><<<dim3(16,4,1), 512, 0, stream>>>(
                xb, wall + WB, k, nullptr, bp + 1024, nullptr,
                1024, 1024, 1024, 16, 0, 0, 0, 0, 0, 0, 0.f);
            gemm8p<0><<<dim3(16,4,1), 512, 0, stream>>>(
                xb, wall + 2*WB, P, nullptr, bp + 2048, nullptr,
                1024, 1024, 1024, 16, 0, 0, 0, 0, 0, 0, 0.f);
            transpose64<<<dim3(64,16,1), 256, 0, stream>>>(P, vt, (int)T, (int)D, 0, 0);
            gemm8p<1><<<dim3(16,16,1), 512, 0, stream>>>(
                q, k, P, nullptr, nullptr, psum,
                1024, 1024, 4096, 16, 0, 0, 0, 0, 0, 0, ALPHA);
            rowsum16<<<16, 256, 0, stream>>>(psum, rs);
            gemm8p<3><<<dim3(16,4,2), 512, 0, stream>>>(
                P, vt, parts, out + b*TD, nullptr, nullptr,
                4096, 4096, 1024, 32, 2048, 2048, TD, 0, 0, 2, 0.f);
            pv_reduce<<<4096, 256, 0, stream>>>(out + b*TD, parts, 1, rs);
        }
    }
}